// Round 5
// baseline (494.892 us; speedup 1.0000x reference)
//
#include <hip/hip_runtime.h>

// PMF rating prediction: out[p] = relu(dot(U[user_ids[p]], V[item_ids[p]])), D=64.
//
// Architecture: deterministic counting sort of pairs by user id, then compute
// in sorted order so each user row is fetched from HBM once.
//
// R5 (from counters): R4's 2048-user buckets gave ZERO fetch reduction
// (487.8MB vs direct 486.6MB) -- bucket reuse distance (~90us) exceeds L3
// turnover (~80us @3.1TB/s). Added subsort_kernel: per-bucket 128-way
// sub-sort to 16-user granularity, so both touches of a user row land
// within a ~32-pair window of one block -> L1/L2 reuse by construction.
// Predicted binned FETCH ~265MB (users 221 once + items 25.6 + recs 16).
// No global atomics anywhere; all blocks <=512 threads.

constexpr int HIDDEN = 64;
constexpr int K = 4;               // pairs per 16-lane group
constexpr int MAX_BUCKETS = 512;   // user-id ranges; also max chunks
constexpr int BASE_CHUNK = 4096;   // pairs per sort chunk (grows if n large)
constexpr int SUBB = 128;          // sub-buckets per bucket (7 bits)

using uint = unsigned int;
using u64 = unsigned long long;

// ---------------------------------------------------------------------------
// Fallback: round-0 kernel (419us harness), used when ws/shape doesn't fit.
// ---------------------------------------------------------------------------
__global__ __launch_bounds__(256) void pmf_dot_kernel(
    const float* __restrict__ user_emb,
    const float* __restrict__ item_emb,
    const int*   __restrict__ user_ids,
    const int*   __restrict__ item_ids,
    float*       __restrict__ out,
    int n_pairs)
{
    const int group  = (blockIdx.x * blockDim.x + threadIdx.x) >> 4;
    const int lane16 = threadIdx.x & 15;
    const int p0     = group * K;

    if (p0 + K <= n_pairs) {
        const int4 u4 = *reinterpret_cast<const int4*>(user_ids + p0);
        const int4 i4 = *reinterpret_cast<const int4*>(item_ids + p0);

        const float4* up0 = reinterpret_cast<const float4*>(user_emb + (size_t)u4.x * HIDDEN) + lane16;
        const float4* up1 = reinterpret_cast<const float4*>(user_emb + (size_t)u4.y * HIDDEN) + lane16;
        const float4* up2 = reinterpret_cast<const float4*>(user_emb + (size_t)u4.z * HIDDEN) + lane16;
        const float4* up3 = reinterpret_cast<const float4*>(user_emb + (size_t)u4.w * HIDDEN) + lane16;
        const float4* vp0 = reinterpret_cast<const float4*>(item_emb + (size_t)i4.x * HIDDEN) + lane16;
        const float4* vp1 = reinterpret_cast<const float4*>(item_emb + (size_t)i4.y * HIDDEN) + lane16;
        const float4* vp2 = reinterpret_cast<const float4*>(item_emb + (size_t)i4.z * HIDDEN) + lane16;
        const float4* vp3 = reinterpret_cast<const float4*>(item_emb + (size_t)i4.w * HIDDEN) + lane16;

        const float4 a0 = *up0, a1 = *up1, a2 = *up2, a3 = *up3;
        const float4 b0 = *vp0, b1 = *vp1, b2 = *vp2, b3 = *vp3;

        float d0 = a0.x * b0.x + a0.y * b0.y + a0.z * b0.z + a0.w * b0.w;
        float d1 = a1.x * b1.x + a1.y * b1.y + a1.z * b1.z + a1.w * b1.w;
        float d2 = a2.x * b2.x + a2.y * b2.y + a2.z * b2.z + a2.w * b2.w;
        float d3 = a3.x * b3.x + a3.y * b3.y + a3.z * b3.z + a3.w * b3.w;

        #pragma unroll
        for (int s = 1; s < 16; s <<= 1) {
            d0 += __shfl_xor(d0, s, 16);
            d1 += __shfl_xor(d1, s, 16);
            d2 += __shfl_xor(d2, s, 16);
            d3 += __shfl_xor(d3, s, 16);
        }

        if (lane16 == 0) {
            float4 r;
            r.x = d0 > 0.0f ? d0 : 0.0f;
            r.y = d1 > 0.0f ? d1 : 0.0f;
            r.z = d2 > 0.0f ? d2 : 0.0f;
            r.w = d3 > 0.0f ? d3 : 0.0f;
            *reinterpret_cast<float4*>(out + p0) = r;
        }
    } else if (p0 < n_pairs) {
        for (int p = p0; p < n_pairs; ++p) {
            const int uid = user_ids[p];
            const int iid = item_ids[p];
            const float4 a = *(reinterpret_cast<const float4*>(user_emb + (size_t)uid * HIDDEN) + lane16);
            const float4 b = *(reinterpret_cast<const float4*>(item_emb + (size_t)iid * HIDDEN) + lane16);
            float d = a.x * b.x + a.y * b.y + a.z * b.z + a.w * b.w;
            #pragma unroll
            for (int s = 1; s < 16; s <<= 1) d += __shfl_xor(d, s, 16);
            if (lane16 == 0) out[p] = d > 0.0f ? d : 0.0f;
        }
    }
}

// ---------------------------------------------------------------------------
// Pass A: per-chunk bucket histogram. One block per chunk, LDS counters only,
// int4 vector id loads, coalesced plain store of the 512 counts.
// ---------------------------------------------------------------------------
__global__ __launch_bounds__(256) void chunk_hist_kernel(
    const int* __restrict__ uids, uint* __restrict__ chunkhist,
    int n, int chunk, int shift)
{
    __shared__ uint h[MAX_BUCKETS];
    for (int i = threadIdx.x; i < MAX_BUCKETS; i += 256) h[i] = 0u;
    __syncthreads();
    const int start = blockIdx.x * chunk;
    const int end   = min(start + chunk, n);
    const int L     = end - start;
    const int L4    = L & ~3;
    for (int i = start + threadIdx.x * 4; i < start + L4; i += 1024) {
        const int4 u4 = *reinterpret_cast<const int4*>(uids + i);
        atomicAdd(&h[min(((uint)u4.x) >> shift, (uint)(MAX_BUCKETS - 1))], 1u);
        atomicAdd(&h[min(((uint)u4.y) >> shift, (uint)(MAX_BUCKETS - 1))], 1u);
        atomicAdd(&h[min(((uint)u4.z) >> shift, (uint)(MAX_BUCKETS - 1))], 1u);
        atomicAdd(&h[min(((uint)u4.w) >> shift, (uint)(MAX_BUCKETS - 1))], 1u);
    }
    for (int i = start + L4 + threadIdx.x; i < end; i += 256)
        atomicAdd(&h[min(((uint)uids[i]) >> shift, (uint)(MAX_BUCKETS - 1))], 1u);
    __syncthreads();
    for (int i = threadIdx.x; i < MAX_BUCKETS; i += 256)
        chunkhist[(size_t)blockIdx.x * MAX_BUCKETS + i] = h[i];
}

// ---------------------------------------------------------------------------
// Pass B1: parallel per-bucket prefix over chunks. Block b handles bucket b.
// ---------------------------------------------------------------------------
__global__ __launch_bounds__(MAX_BUCKETS) void scanB1_kernel(
    const uint* __restrict__ chunkhist, uint* __restrict__ chunkbase,
    uint* __restrict__ btotal, int nchunks)
{
    __shared__ uint tmp[MAX_BUCKETS];
    const int b = blockIdx.x;
    const int t = threadIdx.x;
    const uint v = (t < nchunks) ? chunkhist[(size_t)t * MAX_BUCKETS + b] : 0u;
    tmp[t] = v;
    __syncthreads();
    #pragma unroll
    for (int d = 1; d < MAX_BUCKETS; d <<= 1) {
        const uint w = (t >= d) ? tmp[t - d] : 0u;
        __syncthreads();
        tmp[t] += w;
        __syncthreads();
    }
    if (t < nchunks)
        chunkbase[(size_t)t * MAX_BUCKETS + b] = tmp[t] - v;  // exclusive, no start
    if (t == MAX_BUCKETS - 1) btotal[b] = tmp[t];
}

// ---------------------------------------------------------------------------
// Pass B2: one block: exclusive scan of the 512 bucket totals -> offsets[513].
// ---------------------------------------------------------------------------
__global__ __launch_bounds__(MAX_BUCKETS) void scanB2_kernel(
    const uint* __restrict__ btotal, uint* __restrict__ offsets)
{
    __shared__ uint tmp[MAX_BUCKETS];
    const int t = threadIdx.x;
    tmp[t] = btotal[t];
    __syncthreads();
    #pragma unroll
    for (int d = 1; d < MAX_BUCKETS; d <<= 1) {
        const uint w = (t >= d) ? tmp[t - d] : 0u;
        __syncthreads();
        tmp[t] += w;
        __syncthreads();
    }
    offsets[t] = t ? tmp[t - 1] : 0u;
    if (t == MAX_BUCKETS - 1) offsets[MAX_BUCKETS] = tmp[t];
}

// ---------------------------------------------------------------------------
// Pass C: scatter into bucket order as packed 8B records
// rec = uid | iid<<bits_u | pair_idx<<(bits_u+bits_i). LDS atomics only.
// ---------------------------------------------------------------------------
__global__ __launch_bounds__(256) void scatter_kernel(
    const int* __restrict__ uids, const int* __restrict__ iids,
    const uint* __restrict__ chunkbase, const uint* __restrict__ offsets,
    u64* __restrict__ recs, int n, int chunk, int shift, int bits_u, int bits_i)
{
    __shared__ uint base[MAX_BUCKETS];
    __shared__ uint lcnt[MAX_BUCKETS];
    for (int i = threadIdx.x; i < MAX_BUCKETS; i += 256) {
        base[i] = chunkbase[(size_t)blockIdx.x * MAX_BUCKETS + i] + offsets[i];
        lcnt[i] = 0u;
    }
    __syncthreads();
    const int start = blockIdx.x * chunk;
    const int end   = min(start + chunk, n);
    for (int i = start + threadIdx.x; i < end; i += 256) {
        const uint u = (uint)uids[i];
        const uint v = (uint)iids[i];
        const uint b = min(u >> shift, (uint)(MAX_BUCKETS - 1));
        const uint slot = base[b] + atomicAdd(&lcnt[b], 1u);  // LDS atomic
        if (slot < (uint)n)   // always true; belt-and-braces
            recs[slot] = (u64)u | ((u64)v << bits_u) | ((u64)(uint)i << (bits_u + bits_i));
    }
}

// ---------------------------------------------------------------------------
// Pass C2 (NEW): per-bucket 128-way sub-sort to 16-user granularity.
// One block per bucket. Sweep 1: LDS histogram of sub-bucket (bits
// [subshift, subshift+7) of uid). LDS scan. Sweep 2: scatter recs->recs2
// within the segment (segment is L2-hot after sweep 1). LDS atomics only;
// dst in [s,e) by construction. After this, both touches of a user row sit
// within a ~32-pair window -> L1/L2 reuse in the compute pass.
// ---------------------------------------------------------------------------
__global__ __launch_bounds__(256) void subsort_kernel(
    const u64* __restrict__ recs, u64* __restrict__ recs2,
    const uint* __restrict__ offsets, int subshift, u64 mu)
{
    const uint s = offsets[blockIdx.x];
    const uint e = offsets[blockIdx.x + 1];
    __shared__ uint h[SUBB];
    __shared__ uint tmp[SUBB];
    __shared__ uint base[SUBB];
    __shared__ uint cnt[SUBB];
    const int t = threadIdx.x;
    if (t < SUBB) h[t] = 0u;
    __syncthreads();
    for (uint i = s + t; i < e; i += 256) {
        const uint uid = (uint)(recs[i] & mu);
        atomicAdd(&h[(uid >> subshift) & (SUBB - 1)], 1u);
    }
    __syncthreads();
    const uint v = (t < SUBB) ? h[t] : 0u;
    if (t < SUBB) tmp[t] = v;
    __syncthreads();
    #pragma unroll
    for (int d = 1; d < SUBB; d <<= 1) {
        uint w = 0u;
        if (t < SUBB && t >= d) w = tmp[t - d];
        __syncthreads();
        if (t < SUBB) tmp[t] += w;
        __syncthreads();
    }
    if (t < SUBB) { base[t] = tmp[t] - v; cnt[t] = 0u; }
    __syncthreads();
    for (uint i = s + t; i < e; i += 256) {
        const u64 rec = recs[i];
        const uint sb = ((uint)(rec & mu) >> subshift) & (SUBB - 1);
        const uint dst = s + base[sb] + atomicAdd(&cnt[sb], 1u);  // LDS atomic
        if (dst < e)   // always true; belt-and-braces
            recs2[dst] = rec;
    }
}

// ---------------------------------------------------------------------------
// Pass D: binned compute over sub-sorted records. 4 blocks x 256 threads per
// bucket; 16-lane groups, K=4 pairs, 8 float4 gathers in flight per thread.
// With 16-user sub-sort, repeated uids are adjacent -> user rows HBM-fetched
// once (221MB compulsory), repeats hit L1/L2.
// ---------------------------------------------------------------------------
__global__ __launch_bounds__(256) void pmf_binned_kernel(
    const float* __restrict__ user_emb,
    const float* __restrict__ item_emb,
    const uint*  __restrict__ offsets,
    const u64*   __restrict__ recs,
    float*       __restrict__ out,
    int bits_u, int bits_i)
{
    const int bucket = blockIdx.x >> 2;
    const uint s = offsets[bucket];
    const uint e = offsets[bucket + 1];
    const int lane16 = threadIdx.x & 15;
    const int g = ((blockIdx.x & 3) << 4) | (threadIdx.x >> 4);  // 0..63

    const u64 mu = ((u64)1 << bits_u) - 1;
    const u64 mi = ((u64)1 << bits_i) - 1;

    for (uint q = s + (uint)g * 4u; q < e; q += 256u) {
        uint idx = q + (uint)(lane16 & 3);
        if (idx >= e) idx = e - 1;          // q<e so e>=1; clamp, masked at store
        const u64 rec = recs[idx];          // lanes 0-3 hold the 4 pairs
        const int uu = (int)(rec & mu);
        const int vv = (int)((rec >> bits_u) & mi);

        const int u0 = __shfl(uu, 0, 16), i0 = __shfl(vv, 0, 16);
        const int u1 = __shfl(uu, 1, 16), i1 = __shfl(vv, 1, 16);
        const int u2 = __shfl(uu, 2, 16), i2 = __shfl(vv, 2, 16);
        const int u3 = __shfl(uu, 3, 16), i3 = __shfl(vv, 3, 16);

        const float4* up0 = reinterpret_cast<const float4*>(user_emb + (size_t)u0 * HIDDEN) + lane16;
        const float4* up1 = reinterpret_cast<const float4*>(user_emb + (size_t)u1 * HIDDEN) + lane16;
        const float4* up2 = reinterpret_cast<const float4*>(user_emb + (size_t)u2 * HIDDEN) + lane16;
        const float4* up3 = reinterpret_cast<const float4*>(user_emb + (size_t)u3 * HIDDEN) + lane16;
        const float4* vp0 = reinterpret_cast<const float4*>(item_emb + (size_t)i0 * HIDDEN) + lane16;
        const float4* vp1 = reinterpret_cast<const float4*>(item_emb + (size_t)i1 * HIDDEN) + lane16;
        const float4* vp2 = reinterpret_cast<const float4*>(item_emb + (size_t)i2 * HIDDEN) + lane16;
        const float4* vp3 = reinterpret_cast<const float4*>(item_emb + (size_t)i3 * HIDDEN) + lane16;

        // Issue all 8 gathers before any use so they overlap.
        const float4 a0 = *up0, a1 = *up1, a2 = *up2, a3 = *up3;
        const float4 b0 = *vp0, b1 = *vp1, b2 = *vp2, b3 = *vp3;

        float d0 = a0.x * b0.x + a0.y * b0.y + a0.z * b0.z + a0.w * b0.w;
        float d1 = a1.x * b1.x + a1.y * b1.y + a1.z * b1.z + a1.w * b1.w;
        float d2 = a2.x * b2.x + a2.y * b2.y + a2.z * b2.z + a2.w * b2.w;
        float d3 = a3.x * b3.x + a3.y * b3.y + a3.z * b3.z + a3.w * b3.w;

        #pragma unroll
        for (int sft = 1; sft < 16; sft <<= 1) {
            d0 += __shfl_xor(d0, sft, 16);
            d1 += __shfl_xor(d1, sft, 16);
            d2 += __shfl_xor(d2, sft, 16);
            d3 += __shfl_xor(d3, sft, 16);
        }

        // Lanes 0-3 each hold their own pair's record (idx = original index).
        if (lane16 < 4 && (q + (uint)lane16) < e) {
            const float d = lane16 == 0 ? d0 : lane16 == 1 ? d1 : lane16 == 2 ? d2 : d3;
            out[(uint)(rec >> (bits_u + bits_i))] = d > 0.0f ? d : 0.0f;
        }
    }
}

// ---------------------------------------------------------------------------
extern "C" void kernel_launch(void* const* d_in, const int* in_sizes, int n_in,
                              void* d_out, int out_size, void* d_ws, size_t ws_size,
                              hipStream_t stream) {
    const float* user_emb = (const float*)d_in[0];
    const float* item_emb = (const float*)d_in[1];
    const int*   user_ids = (const int*)d_in[2];
    const int*   item_ids = (const int*)d_in[3];
    float* out = (float*)d_out;

    const int n_pairs = in_sizes[2];                 // 2,000,000

    // Shape-derived constants (bench: 1M users, 100K items, 2M pairs).
    const long long n_users = (long long)in_sizes[0] / HIDDEN;
    const long long n_items = (long long)in_sizes[1] / HIDDEN;

    // Bucket shift: 11 -> 2048 users/bucket covers uid < 512*2048 = 1,048,576.
    // Kernels clamp the bucket index, so it is always in range regardless.
    int shift = 11;
    while (n_users > 0 && (((n_users - 1) >> shift) >= MAX_BUCKETS)) ++shift;
    const int subshift = shift - 7;  // 128 sub-buckets of 2^(shift-7) users

    // Packed-record bit widths.
    auto bits_for = [](long long v) { int b = 1; while ((1ll << b) < v) ++b; return b; };
    const int bits_u = bits_for(n_users > 1 ? n_users : 2);
    const int bits_i = bits_for(n_items > 1 ? n_items : 2);
    const int bits_p = bits_for(n_pairs > 1 ? n_pairs : 2);

    // Chunk size: <= MAX_BUCKETS chunks.
    int chunk = BASE_CHUNK;
    while ((n_pairs + chunk - 1) / chunk > MAX_BUCKETS) chunk <<= 1;
    const int nchunks = (n_pairs + chunk - 1) / chunk;

    // Workspace layout (every word written before read in stream order):
    //   [0, 4096)            : offsets uint[513] (+pad)
    //   [4096, 8192)         : btotal  uint[512] (+pad)
    //   [8192, 8192+1MB)     : chunkhist uint[512*512]
    //   [+1MB, +2MB)         : chunkbase uint[512*512]
    //   [+2MB, +2MB+8n)      : recs  u64[n_pairs]
    //   [+2MB+8n, +2MB+16n)  : recs2 u64[n_pairs]   (optional, sub-sorted)
    const size_t META = 8192 + 2ull * MAX_BUCKETS * MAX_BUCKETS * sizeof(uint);
    const size_t ws_need1 = META + (size_t)n_pairs * sizeof(u64);
    const size_t ws_need2 = META + 2ull * (size_t)n_pairs * sizeof(u64);

    const bool ok_shape = !(n_pairs < BASE_CHUNK || bits_u + bits_i + bits_p > 64 ||
                            n_users <= 0 || n_items <= 0);

    if (d_ws == nullptr || ws_size < ws_need1 || !ok_shape) {
        // Fallback: round-0 direct kernel.
        const int threads = 256;
        const int pairs_per_block = (threads / 16) * K;  // 64 pairs/block
        const int blocks = (n_pairs + pairs_per_block - 1) / pairs_per_block;
        pmf_dot_kernel<<<blocks, threads, 0, stream>>>(
            user_emb, item_emb, user_ids, item_ids, out, n_pairs);
        return;
    }

    uint* offsets   = (uint*)d_ws;                                   // [513]
    uint* btotal    = (uint*)((char*)d_ws + 4096);                   // [512]
    uint* chunkhist = (uint*)((char*)d_ws + 8192);                   // [512*512]
    uint* chunkbase = chunkhist + (size_t)MAX_BUCKETS * MAX_BUCKETS; // [512*512]
    u64*  recs      = (u64*)((char*)d_ws + META);                    // [n_pairs]
    u64*  recs2     = recs + n_pairs;                                // [n_pairs]

    const bool do_subsort = (ws_size >= ws_need2) && (subshift >= 0);

    chunk_hist_kernel<<<nchunks, 256, 0, stream>>>(
        user_ids, chunkhist, n_pairs, chunk, shift);
    scanB1_kernel<<<MAX_BUCKETS, MAX_BUCKETS, 0, stream>>>(
        chunkhist, chunkbase, btotal, nchunks);
    scanB2_kernel<<<1, MAX_BUCKETS, 0, stream>>>(btotal, offsets);
    scatter_kernel<<<nchunks, 256, 0, stream>>>(
        user_ids, item_ids, chunkbase, offsets, recs, n_pairs, chunk, shift,
        bits_u, bits_i);

    const u64* drecs = recs;
    if (do_subsort) {
        const u64 mu = ((u64)1 << bits_u) - 1;
        subsort_kernel<<<MAX_BUCKETS, 256, 0, stream>>>(
            recs, recs2, offsets, subshift, mu);
        drecs = recs2;
    }

    pmf_binned_kernel<<<MAX_BUCKETS * 4, 256, 0, stream>>>(
        user_emb, item_emb, offsets, drecs, out, bits_u, bits_i);
}

// Round 7
// 472.462 us; speedup vs baseline: 1.0475x; 1.0475x over previous
//
#include <hip/hip_runtime.h>

// PMF rating prediction: out[p] = relu(dot(U[user_ids[p]], V[item_ids[p]])), D=64.
//
// Architecture: counting sort of pairs into 512 user-id-range buckets
// (hist -> scans -> scatter), then ONE fused kernel per half-bucket that
// sub-sorts its contiguous segment into LDS at 16-user granularity and
// computes from LDS. All reuse of a user row happens within one CU
// (L1/MSHR-merged), fixing R5's cross-XCD simultaneous-miss problem
// (377MB fetch, only half the reuse captured).
//
// R7: identical to R6 minus __builtin_nontemporal_store (the only element
// never exercised in a passing run; R6 failed infra twice). Plain 4B
// stores as in the passing R4/R5 runs. No global atomics anywhere.

constexpr int HIDDEN = 64;
constexpr int K = 4;               // pairs per 16-lane group (fallback kernel)
constexpr int MAX_BUCKETS = 512;   // user-id ranges; also max chunks
constexpr int BASE_CHUNK = 4096;   // pairs per sort chunk (grows if n large)
constexpr int SUBB = 128;          // sub-buckets per half-segment
constexpr int MAXSEG = 2560;       // max records LDS-sortable per half-bucket

using uint = unsigned int;
using u64 = unsigned long long;

// ---------------------------------------------------------------------------
// Fallback: round-0 kernel (419us harness), used when ws/shape doesn't fit.
// ---------------------------------------------------------------------------
__global__ __launch_bounds__(256) void pmf_dot_kernel(
    const float* __restrict__ user_emb,
    const float* __restrict__ item_emb,
    const int*   __restrict__ user_ids,
    const int*   __restrict__ item_ids,
    float*       __restrict__ out,
    int n_pairs)
{
    const int group  = (blockIdx.x * blockDim.x + threadIdx.x) >> 4;
    const int lane16 = threadIdx.x & 15;
    const int p0     = group * K;

    if (p0 + K <= n_pairs) {
        const int4 u4 = *reinterpret_cast<const int4*>(user_ids + p0);
        const int4 i4 = *reinterpret_cast<const int4*>(item_ids + p0);

        const float4* up0 = reinterpret_cast<const float4*>(user_emb + (size_t)u4.x * HIDDEN) + lane16;
        const float4* up1 = reinterpret_cast<const float4*>(user_emb + (size_t)u4.y * HIDDEN) + lane16;
        const float4* up2 = reinterpret_cast<const float4*>(user_emb + (size_t)u4.z * HIDDEN) + lane16;
        const float4* up3 = reinterpret_cast<const float4*>(user_emb + (size_t)u4.w * HIDDEN) + lane16;
        const float4* vp0 = reinterpret_cast<const float4*>(item_emb + (size_t)i4.x * HIDDEN) + lane16;
        const float4* vp1 = reinterpret_cast<const float4*>(item_emb + (size_t)i4.y * HIDDEN) + lane16;
        const float4* vp2 = reinterpret_cast<const float4*>(item_emb + (size_t)i4.z * HIDDEN) + lane16;
        const float4* vp3 = reinterpret_cast<const float4*>(item_emb + (size_t)i4.w * HIDDEN) + lane16;

        const float4 a0 = *up0, a1 = *up1, a2 = *up2, a3 = *up3;
        const float4 b0 = *vp0, b1 = *vp1, b2 = *vp2, b3 = *vp3;

        float d0 = a0.x * b0.x + a0.y * b0.y + a0.z * b0.z + a0.w * b0.w;
        float d1 = a1.x * b1.x + a1.y * b1.y + a1.z * b1.z + a1.w * b1.w;
        float d2 = a2.x * b2.x + a2.y * b2.y + a2.z * b2.z + a2.w * b2.w;
        float d3 = a3.x * b3.x + a3.y * b3.y + a3.z * b3.z + a3.w * b3.w;

        #pragma unroll
        for (int s = 1; s < 16; s <<= 1) {
            d0 += __shfl_xor(d0, s, 16);
            d1 += __shfl_xor(d1, s, 16);
            d2 += __shfl_xor(d2, s, 16);
            d3 += __shfl_xor(d3, s, 16);
        }

        if (lane16 == 0) {
            float4 r;
            r.x = d0 > 0.0f ? d0 : 0.0f;
            r.y = d1 > 0.0f ? d1 : 0.0f;
            r.z = d2 > 0.0f ? d2 : 0.0f;
            r.w = d3 > 0.0f ? d3 : 0.0f;
            *reinterpret_cast<float4*>(out + p0) = r;
        }
    } else if (p0 < n_pairs) {
        for (int p = p0; p < n_pairs; ++p) {
            const int uid = user_ids[p];
            const int iid = item_ids[p];
            const float4 a = *(reinterpret_cast<const float4*>(user_emb + (size_t)uid * HIDDEN) + lane16);
            const float4 b = *(reinterpret_cast<const float4*>(item_emb + (size_t)iid * HIDDEN) + lane16);
            float d = a.x * b.x + a.y * b.y + a.z * b.z + a.w * b.w;
            #pragma unroll
            for (int s = 1; s < 16; s <<= 1) d += __shfl_xor(d, s, 16);
            if (lane16 == 0) out[p] = d > 0.0f ? d : 0.0f;
        }
    }
}

// ---------------------------------------------------------------------------
// Pass A: per-chunk bucket histogram. One block per chunk, LDS counters only,
// int4 vector id loads, coalesced plain store of the 512 counts.
// ---------------------------------------------------------------------------
__global__ __launch_bounds__(256) void chunk_hist_kernel(
    const int* __restrict__ uids, uint* __restrict__ chunkhist,
    int n, int chunk, int shift)
{
    __shared__ uint h[MAX_BUCKETS];
    for (int i = threadIdx.x; i < MAX_BUCKETS; i += 256) h[i] = 0u;
    __syncthreads();
    const int start = blockIdx.x * chunk;
    const int end   = min(start + chunk, n);
    const int L     = end - start;
    const int L4    = L & ~3;
    for (int i = start + threadIdx.x * 4; i < start + L4; i += 1024) {
        const int4 u4 = *reinterpret_cast<const int4*>(uids + i);
        atomicAdd(&h[min(((uint)u4.x) >> shift, (uint)(MAX_BUCKETS - 1))], 1u);
        atomicAdd(&h[min(((uint)u4.y) >> shift, (uint)(MAX_BUCKETS - 1))], 1u);
        atomicAdd(&h[min(((uint)u4.z) >> shift, (uint)(MAX_BUCKETS - 1))], 1u);
        atomicAdd(&h[min(((uint)u4.w) >> shift, (uint)(MAX_BUCKETS - 1))], 1u);
    }
    for (int i = start + L4 + threadIdx.x; i < end; i += 256)
        atomicAdd(&h[min(((uint)uids[i]) >> shift, (uint)(MAX_BUCKETS - 1))], 1u);
    __syncthreads();
    for (int i = threadIdx.x; i < MAX_BUCKETS; i += 256)
        chunkhist[(size_t)blockIdx.x * MAX_BUCKETS + i] = h[i];
}

// ---------------------------------------------------------------------------
// Pass B1: parallel per-bucket prefix over chunks. Block b handles bucket b.
// ---------------------------------------------------------------------------
__global__ __launch_bounds__(MAX_BUCKETS) void scanB1_kernel(
    const uint* __restrict__ chunkhist, uint* __restrict__ chunkbase,
    uint* __restrict__ btotal, int nchunks)
{
    __shared__ uint tmp[MAX_BUCKETS];
    const int b = blockIdx.x;
    const int t = threadIdx.x;
    const uint v = (t < nchunks) ? chunkhist[(size_t)t * MAX_BUCKETS + b] : 0u;
    tmp[t] = v;
    __syncthreads();
    #pragma unroll
    for (int d = 1; d < MAX_BUCKETS; d <<= 1) {
        const uint w = (t >= d) ? tmp[t - d] : 0u;
        __syncthreads();
        tmp[t] += w;
        __syncthreads();
    }
    if (t < nchunks)
        chunkbase[(size_t)t * MAX_BUCKETS + b] = tmp[t] - v;  // exclusive, no start
    if (t == MAX_BUCKETS - 1) btotal[b] = tmp[t];
}

// ---------------------------------------------------------------------------
// Pass B2: one block: exclusive scan of the 512 bucket totals -> offsets[513].
// ---------------------------------------------------------------------------
__global__ __launch_bounds__(MAX_BUCKETS) void scanB2_kernel(
    const uint* __restrict__ btotal, uint* __restrict__ offsets)
{
    __shared__ uint tmp[MAX_BUCKETS];
    const int t = threadIdx.x;
    tmp[t] = btotal[t];
    __syncthreads();
    #pragma unroll
    for (int d = 1; d < MAX_BUCKETS; d <<= 1) {
        const uint w = (t >= d) ? tmp[t - d] : 0u;
        __syncthreads();
        tmp[t] += w;
        __syncthreads();
    }
    offsets[t] = t ? tmp[t - 1] : 0u;
    if (t == MAX_BUCKETS - 1) offsets[MAX_BUCKETS] = tmp[t];
}

// ---------------------------------------------------------------------------
// Pass C: scatter into bucket order as packed 8B records
// rec = uid | iid<<bits_u | pair_idx<<(bits_u+bits_i). LDS atomics only;
// int4 vector id loads.
// ---------------------------------------------------------------------------
__global__ __launch_bounds__(256) void scatter_kernel(
    const int* __restrict__ uids, const int* __restrict__ iids,
    const uint* __restrict__ chunkbase, const uint* __restrict__ offsets,
    u64* __restrict__ recs, int n, int chunk, int shift, int bits_u, int bits_i)
{
    __shared__ uint base[MAX_BUCKETS];
    __shared__ uint lcnt[MAX_BUCKETS];
    for (int i = threadIdx.x; i < MAX_BUCKETS; i += 256) {
        base[i] = chunkbase[(size_t)blockIdx.x * MAX_BUCKETS + i] + offsets[i];
        lcnt[i] = 0u;
    }
    __syncthreads();
    const int start = blockIdx.x * chunk;
    const int end   = min(start + chunk, n);
    const int L     = end - start;
    const int L4    = L & ~3;
    for (int i = start + threadIdx.x * 4; i < start + L4; i += 1024) {
        const int4 u4 = *reinterpret_cast<const int4*>(uids + i);
        const int4 i4 = *reinterpret_cast<const int4*>(iids + i);
        const int us[4] = {u4.x, u4.y, u4.z, u4.w};
        const int vs[4] = {i4.x, i4.y, i4.z, i4.w};
        #pragma unroll
        for (int k = 0; k < 4; ++k) {
            const uint u = (uint)us[k];
            const uint b = min(u >> shift, (uint)(MAX_BUCKETS - 1));
            const uint slot = base[b] + atomicAdd(&lcnt[b], 1u);  // LDS atomic
            if (slot < (uint)n)
                recs[slot] = (u64)u | ((u64)(uint)vs[k] << bits_u)
                           | ((u64)(uint)(i + k) << (bits_u + bits_i));
        }
    }
    for (int i = start + L4 + threadIdx.x; i < end; i += 256) {
        const uint u = (uint)uids[i];
        const uint b = min(u >> shift, (uint)(MAX_BUCKETS - 1));
        const uint slot = base[b] + atomicAdd(&lcnt[b], 1u);
        if (slot < (uint)n)
            recs[slot] = (u64)u | ((u64)(uint)iids[i] << bits_u)
                       | ((u64)(uint)i << (bits_u + bits_i));
    }
}

// ---------------------------------------------------------------------------
// Pass D (fused sub-sort + compute): 2 blocks per bucket, each owns a
// CONTIGUOUS half-segment (~2048 recs). Sweep 1: histogram 128 sub-buckets
// (16-user bins). LDS scan. Sweep 2: re-read (L1/L2-hot) and place sorted
// records in LDS. Compute from LDS: both touches of a user row now occur on
// THIS CU within a ~64-record window -> L1/MSHR-merged -> each user row
// HBM-fetched once. Segments > MAXSEG (adversarial only) compute unsorted
// from global: correct, just slower. use_lds is block-uniform (no divergent
// barriers).
// ---------------------------------------------------------------------------
__global__ __launch_bounds__(256) void pmf_fused_kernel(
    const float* __restrict__ user_emb,
    const float* __restrict__ item_emb,
    const uint*  __restrict__ offsets,
    const u64*   __restrict__ recs,
    float*       __restrict__ out,
    int bits_u, int bits_i, int subshift)
{
    __shared__ u64  lrec[MAXSEG];
    __shared__ uint h[SUBB];
    __shared__ uint tmp[SUBB];
    __shared__ uint sbase[SUBB];
    __shared__ uint scnt[SUBB];

    const int  bucket = blockIdx.x >> 1;
    const int  half   = blockIdx.x & 1;
    const uint s0 = offsets[bucket];
    const uint e0 = offsets[bucket + 1];
    const uint len0 = e0 - s0;
    const uint mid  = s0 + ((len0 + 1u) >> 1);
    const uint s   = half ? mid : s0;
    const uint e   = half ? e0  : mid;
    const uint len = (e > s) ? (e - s) : 0u;

    const int t = threadIdx.x;
    const u64 mu = ((u64)1 << bits_u) - 1;
    const u64 mi = ((u64)1 << bits_i) - 1;

    const bool use_lds = (len > 0u) && (len <= (uint)MAXSEG);
    if (use_lds) {
        if (t < SUBB) h[t] = 0u;
        __syncthreads();
        for (uint i = (uint)t; i < len; i += 256u) {
            const uint uid = (uint)(recs[s + i] & mu);
            atomicAdd(&h[(uid >> subshift) & (SUBB - 1)], 1u);
        }
        __syncthreads();
        const uint v = (t < SUBB) ? h[t] : 0u;
        if (t < SUBB) tmp[t] = v;
        __syncthreads();
        #pragma unroll
        for (int d = 1; d < SUBB; d <<= 1) {
            uint w = 0u;
            if (t < SUBB && t >= d) w = tmp[t - d];
            __syncthreads();
            if (t < SUBB) tmp[t] += w;
            __syncthreads();
        }
        if (t < SUBB) { sbase[t] = tmp[t] - v; scnt[t] = 0u; }
        __syncthreads();
        for (uint i = (uint)t; i < len; i += 256u) {
            const u64 r = recs[s + i];              // L1/L2-hot re-read
            const uint sb = ((uint)(r & mu) >> subshift) & (SUBB - 1);
            const uint dst = sbase[sb] + atomicAdd(&scnt[sb], 1u);  // LDS atomic
            if (dst < (uint)MAXSEG)                  // always true
                lrec[dst] = r;
        }
        __syncthreads();
    }

    const int lane16 = t & 15;
    const int g = t >> 4;   // 0..15 groups of 16 lanes, K=4 pairs each

    for (uint q = (uint)g * 4u; q < len; q += 64u) {
        uint idx = q + (uint)(lane16 & 3);
        if (idx >= len) idx = len - 1u;   // clamp; masked at store
        const u64 rec = use_lds ? lrec[idx] : recs[s + idx];
        const int uu = (int)(rec & mu);
        const int vv = (int)((rec >> bits_u) & mi);

        const int u0 = __shfl(uu, 0, 16), i0 = __shfl(vv, 0, 16);
        const int u1 = __shfl(uu, 1, 16), i1 = __shfl(vv, 1, 16);
        const int u2 = __shfl(uu, 2, 16), i2 = __shfl(vv, 2, 16);
        const int u3 = __shfl(uu, 3, 16), i3 = __shfl(vv, 3, 16);

        const float4* up0 = reinterpret_cast<const float4*>(user_emb + (size_t)u0 * HIDDEN) + lane16;
        const float4* up1 = reinterpret_cast<const float4*>(user_emb + (size_t)u1 * HIDDEN) + lane16;
        const float4* up2 = reinterpret_cast<const float4*>(user_emb + (size_t)u2 * HIDDEN) + lane16;
        const float4* up3 = reinterpret_cast<const float4*>(user_emb + (size_t)u3 * HIDDEN) + lane16;
        const float4* vp0 = reinterpret_cast<const float4*>(item_emb + (size_t)i0 * HIDDEN) + lane16;
        const float4* vp1 = reinterpret_cast<const float4*>(item_emb + (size_t)i1 * HIDDEN) + lane16;
        const float4* vp2 = reinterpret_cast<const float4*>(item_emb + (size_t)i2 * HIDDEN) + lane16;
        const float4* vp3 = reinterpret_cast<const float4*>(item_emb + (size_t)i3 * HIDDEN) + lane16;

        // Issue all 8 gathers before any use so they overlap.
        const float4 a0 = *up0, a1 = *up1, a2 = *up2, a3 = *up3;
        const float4 b0 = *vp0, b1 = *vp1, b2 = *vp2, b3 = *vp3;

        float d0 = a0.x * b0.x + a0.y * b0.y + a0.z * b0.z + a0.w * b0.w;
        float d1 = a1.x * b1.x + a1.y * b1.y + a1.z * b1.z + a1.w * b1.w;
        float d2 = a2.x * b2.x + a2.y * b2.y + a2.z * b2.z + a2.w * b2.w;
        float d3 = a3.x * b3.x + a3.y * b3.y + a3.z * b3.z + a3.w * b3.w;

        #pragma unroll
        for (int sft = 1; sft < 16; sft <<= 1) {
            d0 += __shfl_xor(d0, sft, 16);
            d1 += __shfl_xor(d1, sft, 16);
            d2 += __shfl_xor(d2, sft, 16);
            d3 += __shfl_xor(d3, sft, 16);
        }

        if (lane16 < 4 && (q + (uint)lane16) < len) {
            const float d = lane16 == 0 ? d0 : lane16 == 1 ? d1 : lane16 == 2 ? d2 : d3;
            out[(uint)(rec >> (bits_u + bits_i))] = d > 0.0f ? d : 0.0f;
        }
    }
}

// ---------------------------------------------------------------------------
extern "C" void kernel_launch(void* const* d_in, const int* in_sizes, int n_in,
                              void* d_out, int out_size, void* d_ws, size_t ws_size,
                              hipStream_t stream) {
    const float* user_emb = (const float*)d_in[0];
    const float* item_emb = (const float*)d_in[1];
    const int*   user_ids = (const int*)d_in[2];
    const int*   item_ids = (const int*)d_in[3];
    float* out = (float*)d_out;

    const int n_pairs = in_sizes[2];                 // 2,000,000

    // Shape-derived constants (bench: 1M users, 100K items, 2M pairs).
    const long long n_users = (long long)in_sizes[0] / HIDDEN;
    const long long n_items = (long long)in_sizes[1] / HIDDEN;

    // Bucket shift: 11 -> 2048 users/bucket covers uid < 512*2048 = 1,048,576.
    // Kernels clamp the bucket index, so it is always in range regardless.
    int shift = 11;
    while (n_users > 0 && (((n_users - 1) >> shift) >= MAX_BUCKETS)) ++shift;
    const int subshift = shift - 7;  // 128 sub-buckets of 2^(shift-7) users

    // Packed-record bit widths.
    auto bits_for = [](long long v) { int b = 1; while ((1ll << b) < v) ++b; return b; };
    const int bits_u = bits_for(n_users > 1 ? n_users : 2);
    const int bits_i = bits_for(n_items > 1 ? n_items : 2);
    const int bits_p = bits_for(n_pairs > 1 ? n_pairs : 2);

    // Chunk size: <= MAX_BUCKETS chunks.
    int chunk = BASE_CHUNK;
    while ((n_pairs + chunk - 1) / chunk > MAX_BUCKETS) chunk <<= 1;
    const int nchunks = (n_pairs + chunk - 1) / chunk;

    // Workspace layout (every word written before read in stream order):
    //   [0, 4096)            : offsets uint[513] (+pad)
    //   [4096, 8192)         : btotal  uint[512] (+pad)
    //   [8192, 8192+1MB)     : chunkhist uint[512*512]
    //   [+1MB, +2MB)         : chunkbase uint[512*512]
    //   [+2MB, +2MB+8n)      : recs  u64[n_pairs]
    const size_t META = 8192 + 2ull * MAX_BUCKETS * MAX_BUCKETS * sizeof(uint);
    const size_t ws_need = META + (size_t)n_pairs * sizeof(u64);

    const bool ok_shape = !(n_pairs < BASE_CHUNK || bits_u + bits_i + bits_p > 64 ||
                            n_users <= 0 || n_items <= 0 || subshift < 0);

    if (d_ws == nullptr || ws_size < ws_need || !ok_shape) {
        // Fallback: round-0 direct kernel.
        const int threads = 256;
        const int pairs_per_block = (threads / 16) * K;  // 64 pairs/block
        const int blocks = (n_pairs + pairs_per_block - 1) / pairs_per_block;
        pmf_dot_kernel<<<blocks, threads, 0, stream>>>(
            user_emb, item_emb, user_ids, item_ids, out, n_pairs);
        return;
    }

    uint* offsets   = (uint*)d_ws;                                   // [513]
    uint* btotal    = (uint*)((char*)d_ws + 4096);                   // [512]
    uint* chunkhist = (uint*)((char*)d_ws + 8192);                   // [512*512]
    uint* chunkbase = chunkhist + (size_t)MAX_BUCKETS * MAX_BUCKETS; // [512*512]
    u64*  recs      = (u64*)((char*)d_ws + META);                    // [n_pairs]

    chunk_hist_kernel<<<nchunks, 256, 0, stream>>>(
        user_ids, chunkhist, n_pairs, chunk, shift);
    scanB1_kernel<<<MAX_BUCKETS, MAX_BUCKETS, 0, stream>>>(
        chunkhist, chunkbase, btotal, nchunks);
    scanB2_kernel<<<1, MAX_BUCKETS, 0, stream>>>(btotal, offsets);
    scatter_kernel<<<nchunks, 256, 0, stream>>>(
        user_ids, item_ids, chunkbase, offsets, recs, n_pairs, chunk, shift,
        bits_u, bits_i);
    pmf_fused_kernel<<<MAX_BUCKETS * 2, 256, 0, stream>>>(
        user_emb, item_emb, offsets, recs, out, bits_u, bits_i, subshift);
}